// Round 7
// baseline (241.470 us; speedup 1.0000x reference)
//
#include <hip/hip_runtime.h>
#include <math.h>

// R10: R8's proven one-shot transaction, minimum delta: 8 rows/block via
// 2 rows/wave (256 threads), uniform 3-slot-per-wave staging, ONE wall.
//
// Model (fits R3..R8): per-CU read throughput is MSHR-capped at ~4-5 B/cy
// when misses go to L3/HBM (every structure hits this; store-only
// fillBuffer does 10.7 B/cy). Occupancy past "miss queue full" buys
// nothing (R8's 16 waves already there) -> the lever is L1-fill traffic:
// R8 stages 9 rows per 4 outputs (2.25x); R10 stages 12 per 8 (1.5x).
//
// R9 (512 thr + divergent staging + launch_bounds(512,6)) killed the
// container twice; R8 (256 thr, uniform staging) ran. R10 keeps R8's
// exact block shape and fully uniform control flow: wave w stages slots
// {w, w+4, w+8} = rows {t0-4+w, t0+w, t0+4+w}, computes rows t0+w and
// t0+4+w. Single __syncthreads. No divergence anywhere.

constexpr int T_DIM = 4096;
constexpr int D_DIM = 1024;
constexpr int NROW  = 8;                 // rows per block (2 per wave)
constexpr int NSLOT = 12;                // staged rows t0-4 .. t0+7 = 48 KB

// ds_swizzle quad-perm broadcast patterns: offset[15]=1, offset[7:0]=2-bit sels
constexpr int QB0 = 0x8000;  // all quad lanes <- quad lane 0
constexpr int QB1 = 0x8055;  // all quad lanes <- quad lane 1
constexpr int QB2 = 0x80AA;  // all quad lanes <- quad lane 2

template <int PAT>
__device__ __forceinline__ float swz(float v) {
    return __int_as_float(__builtin_amdgcn_ds_swizzle(__float_as_int(v), PAT));
}

__device__ __forceinline__ float sigmoidf(float z) {
    return 1.0f / (1.0f + __expf(-z));
}

// async global->LDS, 16B/lane: LDS dest = wave-uniform base + lane*16,
// global src = per-lane address (lane l reads base + l*16 for a linear row)
__device__ __forceinline__ void gld16(const float* g, float* l) {
    __builtin_amdgcn_global_load_lds(
        (const __attribute__((address_space(1))) unsigned int*)g,
        (__attribute__((address_space(3))) unsigned int*)l,
        16, 0, 0);
}

__global__ __launch_bounds__(256, 3) void clifford_kernel(
    const float* __restrict__ x,
    const float* __restrict__ gate_w,
    const float* __restrict__ gate_b,
    const float* __restrict__ scalar_w,
    const float* __restrict__ bivec_w,
    float* __restrict__ out,
    int nblocks)
{
    // XCD-aware swizzle: 4096 blocks (%8==0) -> 512 contiguous blocks per
    // XCD = exactly one batch b per XCD; halo rows shared with the
    // neighboring block are same-XCD L2 hits.
    int blk = blockIdx.x;
    if ((gridDim.x & 7) == 0) {
        const int per = gridDim.x >> 3;
        blk = (blockIdx.x & 7) * per + (blockIdx.x >> 3);
    }
    if (blk >= nblocks) return;

    const int tid  = threadIdx.x;
    const int wid  = tid >> 6;            // wave w: rows t0+w and t0+4+w
    const int lane = tid & 63;
    const int sub  = lane & 3;
    const int coff = lane << 2;           // float offset of this lane's float4

    const int rpb = T_DIM / NROW;         // row-groups per batch = 512
    const int b   = blk / rpb;
    const int t0  = (blk - b * rpb) * NROW;

    const float* __restrict__ xb = x + (size_t)b * T_DIM * D_DIM;

    __shared__ float ring[NSLOT * D_DIM];     // 12 rows x 4 KB = 48 KB

    // ---- stage slots 0..11 = rows t0-4 .. t0+7; wave w does slots
    // w, w+4, w+8 (identical control flow on all 4 waves). ----
    #pragma unroll
    for (int p = 0; p < 3; ++p) {
        const int q    = p * 4 + wid;                    // slot 0..11
        const int trow = (t0 + q - 4) & (T_DIM - 1);     // circular == jnp.roll
        const float* g = xb + (size_t)trow * D_DIM + coff;
        float* l       = &ring[q * D_DIM];               // wave-uniform base
        #pragma unroll
        for (int m = 0; m < 4; ++m)
            gld16(g + (m << 8), l + (m << 8));
    }

    // gate weights as plain VGPR loads (drained by the same single wall)
    float4 gv[4];
    #pragma unroll
    for (int m = 0; m < 4; ++m)
        gv[m] = *(const float4*)(gate_w + coff + (m << 8));

    const float ss = sigmoidf(scalar_w[0]);
    const float sb = sigmoidf(bivec_w[0]);
    const float gb = gate_b[0];

    // C0 diagonal signs for this lane's 4 blades (full table:
    // {1,1,1,-1, 1,-1,-1,-1, -1,1,1,1, 1,1,1,-1})
    float4 ws;
    if      (sub == 0) ws = make_float4( 1.f,  1.f,  1.f, -1.f);
    else if (sub == 1) ws = make_float4( 1.f, -1.f, -1.f, -1.f);
    else if (sub == 2) ws = make_float4(-1.f,  1.f,  1.f,  1.f);
    else               ws = make_float4( 1.f,  1.f,  1.f, -1.f);
    const float m3  = (sub == 0) ? 1.f : 0.f;   // elem3 <- k=3
    const float a1  = (sub == 1) ? 1.f : 0.f;   // elem1<-k=5, elem2<-k=6
    const float a2  = (sub == 2) ? 1.f : 0.f;   // elem1<-k=9, elem2<-k=10
    const float m12 = (sub == 3) ? 1.f : 0.f;   // elem0 <- k=12

    __syncthreads();   // THE single wall: drains gld16s + gv, then barrier

    // ---- compute 2 rows: r = 0 -> row t0+wid (slot wid+4),
    //                      r = 1 -> row t0+4+wid (slot wid+8) ----
    #pragma unroll
    for (int r = 0; r < 2; ++r) {
        const int lq = wid + 4 + r * 4;              // slot of cur row
        const float* rc  = &ring[(lq)     * D_DIM] + coff;
        const float* rp1 = &ring[(lq - 1) * D_DIM] + coff;
        const float* rp2 = &ring[(lq - 2) * D_DIM] + coff;
        const float* rp4 = &ring[(lq - 4) * D_DIM] + coff;

        float gp = 0.f, sc = 0.f;
        float4 xv[4], dl[4];

        #pragma unroll
        for (int m = 0; m < 4; ++m) {
            xv[m] = *(const float4*)(rc + (m << 8));        // ds_read_b128
            const float4 p1 = *(const float4*)(rp1 + (m << 8));
            const float4 p2 = *(const float4*)(rp2 + (m << 8));
            const float4 p4 = *(const float4*)(rp4 + (m << 8));
            const float4 cur = xv[m];

            float4 cs;  // csum = 3x - x[t-1] - x[t-2] - x[t-4]
            cs.x = 3.f * cur.x - p1.x - p2.x - p4.x;
            cs.y = 3.f * cur.y - p1.y - p2.y - p4.y;
            cs.z = 3.f * cur.z - p1.z - p2.z - p4.z;
            cs.w = 3.f * cur.w - p1.w - p2.w - p4.w;

            gp += cur.x * gv[m].x + cur.y * gv[m].y
                + cur.z * gv[m].z + cur.w * gv[m].w;
            sc += ws.x * (cur.x * cs.x) + ws.y * (cur.y * cs.y)
                + ws.z * (cur.z * cs.z) + ws.w * (cur.w * cs.w);

            // wedge: cross-blade values via quad broadcast (quad = 1 chunk)
            const float x1  = swz<QB0>(cur.y), x2  = swz<QB0>(cur.z);
            const float x4b = swz<QB1>(cur.x), x8b = swz<QB2>(cur.x);
            const float c1  = swz<QB0>(cs.y),  c2  = swz<QB0>(cs.z);
            const float c4b = swz<QB1>(cs.x),  c8b = swz<QB2>(cs.x);

            const float w3  = x1 * c2  - x2  * c1;    // k=3  (e12)
            const float w5  = x1 * c4b - x4b * c1;    // k=5  (e13)
            const float w6  = x2 * c4b - x4b * c2;    // k=6  (e23)
            const float w9  = x1 * c8b - x8b * c1;    // k=9  (e14)
            const float w10 = x2 * c8b - x8b * c2;    // k=10 (e24)
            const float w12 = x4b * c8b - x8b * c4b;  // k=12 (e34)

            dl[m] = make_float4(m12 * w12,
                                a1 * w5 + a2 * w9,
                                a1 * w6 + a2 * w10,
                                m3 * w3);
        }

        // intra-wave butterfly: full-row reduction (wave owns the whole row)
        #pragma unroll
        for (int o = 32; o > 0; o >>= 1) {
            gp += __shfl_xor(gp, o, 64);
            sc += __shfl_xor(sc, o, 64);
        }
        const float gate = sigmoidf(gp + gb);
        const float gsb  = gate * sb;

        const int t = t0 + wid + r * 4;
        float* __restrict__ orow = out + ((size_t)b * T_DIM + t) * D_DIM + coff;
        #pragma unroll
        for (int m = 0; m < 4; ++m) {
            float4 o4;
            o4.x = xv[m].x + gsb * dl[m].x;
            o4.y = xv[m].y + gsb * dl[m].y;
            o4.z = xv[m].z + gsb * dl[m].z;
            o4.w = xv[m].w + gsb * dl[m].w;
            if (m == 0 && lane == 0) o4.x += gate * ss * sc;  // d==0
            *(float4*)(orow + (m << 8)) = o4;
        }
    }
    // no trailing barrier: stores fire and the wave retires
}

extern "C" void kernel_launch(void* const* d_in, const int* in_sizes, int n_in,
                              void* d_out, int out_size, void* d_ws, size_t ws_size,
                              hipStream_t stream) {
    const float* x  = (const float*)d_in[0];
    const float* gw = (const float*)d_in[1];
    const float* gb = (const float*)d_in[2];
    const float* sw = (const float*)d_in[3];
    const float* bw = (const float*)d_in[4];
    float* out = (float*)d_out;

    const int BT      = in_sizes[0] / D_DIM;     // 8*4096 = 32768 rows
    const int nblocks = BT / NROW;               // 4096 blocks
    hipLaunchKernelGGL(clifford_kernel, dim3(nblocks), dim3(256), 0, stream,
                       x, gw, gb, sw, bw, out, nblocks);
}